// Round 1
// baseline (120.394 us; speedup 1.0000x reference)
//
#include <hip/hip_runtime.h>

#define BB 32
#define HH 512
#define WW 512
#define CC 3
#define KK 16
#define NE 19        // K + 3
#define NN (HH * WW) // 262144

__global__ __launch_bounds__(256) void tps_kernel(
    const float* __restrict__ image,        // (B,H,W,C)
    const float* __restrict__ dest_offsets, // (B, 2K)
    const float* __restrict__ right_mat,    // (NE, N)
    const float* __restrict__ L_inv,        // (NE, NE)
    const float* __restrict__ src_pts,      // (2, K)
    float* __restrict__ out)                // (B,H,W,C)
{
    __shared__ float s_coeff[2][NE];
    const int b = blockIdx.y;
    const int tid = threadIdx.x;

    // coeff[p][e] = sum_k (src[p][k] + off[b][p*K+k]) * L_inv[e][3+k]
    if (tid < 2 * NE) {
        const int p = tid / NE;
        const int e = tid % NE;
        float acc = 0.0f;
        #pragma unroll
        for (int k = 0; k < KK; ++k) {
            const float d = src_pts[p * KK + k] + dest_offsets[b * 2 * KK + p * KK + k];
            acc = fmaf(d, L_inv[e * NE + 3 + k], acc);
        }
        s_coeff[p][e] = acc;
    }
    __syncthreads();

    const int n = blockIdx.x * blockDim.x + tid;
    if (n >= NN) return;

    float tx = 0.0f, ty = 0.0f;
    #pragma unroll
    for (int e = 0; e < NE; ++e) {
        const float r = right_mat[(size_t)e * NN + n];
        tx = fmaf(s_coeff[0][e], r, tx);
        ty = fmaf(s_coeff[1][e], r, ty);
    }

    float x = 0.5f * (tx + 1.0f) * (float)WW;
    float y = 0.5f * (ty + 1.0f) * (float)HH;

    int x0 = (int)x;   // trunc toward zero, matches astype(int32)
    int x1 = x0 + 1;
    int y0 = (int)y;
    int y1 = y0 + 1;
    x0 = min(max(x0, 0), WW - 1);
    x1 = min(max(x1, 0), WW - 1);
    y0 = min(max(y0, 0), HH - 1);
    y1 = min(max(y1, 0), HH - 1);

    const float x0f = (float)x0, x1f = (float)x1;
    const float y0f = (float)y0, y1f = (float)y1;
    const float wa = (x1f - x) * (y1f - y);
    const float wb = (x1f - x) * (y - y0f);
    const float wc = (x - x0f) * (y1f - y);
    const float wd = (x - x0f) * (y - y0f);

    const float* __restrict__ img = image + (size_t)b * NN * CC;
    const float* __restrict__ pa = img + ((size_t)y0 * WW + x0) * CC;
    const float* __restrict__ pb = img + ((size_t)y1 * WW + x0) * CC;
    const float* __restrict__ pc = img + ((size_t)y0 * WW + x1) * CC;
    const float* __restrict__ pd = img + ((size_t)y1 * WW + x1) * CC;

    float* __restrict__ o = out + ((size_t)b * NN + n) * CC;
    #pragma unroll
    for (int c = 0; c < CC; ++c) {
        o[c] = wa * pa[c] + wb * pb[c] + wc * pc[c] + wd * pd[c];
    }
}

extern "C" void kernel_launch(void* const* d_in, const int* in_sizes, int n_in,
                              void* d_out, int out_size, void* d_ws, size_t ws_size,
                              hipStream_t stream) {
    const float* image        = (const float*)d_in[0];
    const float* dest_offsets = (const float*)d_in[1];
    const float* right_mat    = (const float*)d_in[2];
    const float* L_inv        = (const float*)d_in[3];
    const float* src_pts      = (const float*)d_in[4];
    float* out = (float*)d_out;

    dim3 grid(NN / 256, BB);
    dim3 block(256);
    hipLaunchKernelGGL(tps_kernel, grid, block, 0, stream,
                       image, dest_offsets, right_mat, L_inv, src_pts, out);
}

// Round 2
// 99.291 us; speedup vs baseline: 1.2125x; 1.2125x over previous
//
#include <hip/hip_runtime.h>

#define BB 32
#define HH 512
#define WW 512
#define CC 3
#define KK 16
#define NE 19        // K + 3
#define NN (HH * WW) // 262144
#define NCOEFF (BB * 2 * NE)  // 1216

__global__ __launch_bounds__(256) void tps_kernel(
    const float* __restrict__ image,        // (B,H,W,C)
    const float* __restrict__ dest_offsets, // (B, 2K)
    const float* __restrict__ right_mat,    // (NE, N)
    const float* __restrict__ L_inv,        // (NE, NE)
    const float* __restrict__ src_pts,      // (2, K)
    float* __restrict__ out)                // (B,H,W,C)
{
    __shared__ float s_coeff[BB][2][NE];
    const int tid = threadIdx.x;

    // Precompute all batches' TPS coefficients:
    // coeff[b][p][e] = sum_k (src[p][k] + off[b][p*K+k]) * L_inv[e][3+k]
    for (int i = tid; i < NCOEFF; i += 256) {
        const int b = i / (2 * NE);
        const int rem = i - b * (2 * NE);
        const int p = rem / NE;
        const int e = rem - p * NE;
        float acc = 0.0f;
        #pragma unroll
        for (int k = 0; k < KK; ++k) {
            const float d = src_pts[p * KK + k] + dest_offsets[b * 2 * KK + p * KK + k];
            acc = fmaf(d, L_inv[e * NE + 3 + k], acc);
        }
        s_coeff[b][p][e] = acc;
    }
    __syncthreads();

    const int n = blockIdx.x * 256 + tid;

    // Load this pixel's right_mat column once (coalesced per row).
    float rm[NE];
    #pragma unroll
    for (int e = 0; e < NE; ++e)
        rm[e] = right_mat[(size_t)e * NN + n];

    const float* __restrict__ img = image;
    float* __restrict__ o = out + (size_t)n * CC;

    #pragma unroll 2
    for (int b = 0; b < BB; ++b) {
        float tx = 0.0f, ty = 0.0f;
        #pragma unroll
        for (int e = 0; e < NE; ++e) {
            tx = fmaf(s_coeff[b][0][e], rm[e], tx);
            ty = fmaf(s_coeff[b][1][e], rm[e], ty);
        }

        const float x = 0.5f * (tx + 1.0f) * (float)WW;
        const float y = 0.5f * (ty + 1.0f) * (float)HH;

        int x0 = (int)x;   // trunc toward zero, matches astype(int32)
        int x1 = x0 + 1;
        int y0 = (int)y;
        int y1 = y0 + 1;
        x0 = min(max(x0, 0), WW - 1);
        x1 = min(max(x1, 0), WW - 1);
        y0 = min(max(y0, 0), HH - 1);
        y1 = min(max(y1, 0), HH - 1);

        const float x0f = (float)x0, x1f = (float)x1;
        const float y0f = (float)y0, y1f = (float)y1;
        const float wa = (x1f - x) * (y1f - y);
        const float wb = (x1f - x) * (y - y0f);
        const float wc = (x - x0f) * (y1f - y);
        const float wd = (x - x0f) * (y - y0f);

        // Row-pair gather: 6 contiguous floats per row starting at xs = min(x0, W-2).
        // Never OOB: pixels (y, xs) and (y, xs+1) are both inside row y.
        const int xs = min(x0, WW - 2);
        const bool hi_a = (x0 > xs);   // pa lives in the upper pixel of the pair
        const bool hi_c = (x1 > xs);   // pc lives in the upper pixel of the pair

        const float* rowA = img + ((size_t)y0 * WW + xs) * CC;
        const float* rowB = img + ((size_t)y1 * WW + xs) * CC;
        float la[6], lb[6];
        __builtin_memcpy(la, rowA, 6 * sizeof(float));
        __builtin_memcpy(lb, rowB, 6 * sizeof(float));

        #pragma unroll
        for (int c = 0; c < CC; ++c) {
            const float pa = hi_a ? la[c + 3] : la[c];
            const float pc = hi_c ? la[c + 3] : la[c];
            const float pb = hi_a ? lb[c + 3] : lb[c];
            const float pd = hi_c ? lb[c + 3] : lb[c];
            o[(size_t)b * NN * CC + c] = wa * pa + wb * pb + wc * pc + wd * pd;
        }

        img += (size_t)NN * CC;
    }
}

extern "C" void kernel_launch(void* const* d_in, const int* in_sizes, int n_in,
                              void* d_out, int out_size, void* d_ws, size_t ws_size,
                              hipStream_t stream) {
    const float* image        = (const float*)d_in[0];
    const float* dest_offsets = (const float*)d_in[1];
    const float* right_mat    = (const float*)d_in[2];
    const float* L_inv        = (const float*)d_in[3];
    const float* src_pts      = (const float*)d_in[4];
    float* out = (float*)d_out;

    dim3 grid(NN / 256);
    dim3 block(256);
    hipLaunchKernelGGL(tps_kernel, grid, block, 0, stream,
                       image, dest_offsets, right_mat, L_inv, src_pts, out);
}

// Round 3
// 96.066 us; speedup vs baseline: 1.2533x; 1.0336x over previous
//
#include <hip/hip_runtime.h>

#define BB 32
#define HH 512
#define WW 512
#define CC 3
#define KK 16
#define NE 19        // K + 3
#define NN (HH * WW) // 262144
#define BPB 4        // batches per block
#define NCOEFF (BPB * 2 * NE) // 152

__global__ __launch_bounds__(256) void tps_kernel(
    const float* __restrict__ image,        // (B,H,W,C)
    const float* __restrict__ dest_offsets, // (B, 2K)
    const float* __restrict__ right_mat,    // (NE, N)
    const float* __restrict__ L_inv,        // (NE, NE)
    const float* __restrict__ src_pts,      // (2, K)
    float* __restrict__ out)                // (B,H,W,C)
{
    __shared__ float s_coeff[BPB][2][NE];
    const int tid = threadIdx.x;
    const int b0 = blockIdx.y * BPB;

    // TPS coefficients for this block's batch group:
    // coeff[bb][p][e] = sum_k (src[p][k] + off[b][p*K+k]) * L_inv[e][3+k]
    if (tid < NCOEFF) {
        const int bb = tid / (2 * NE);
        const int rem = tid - bb * (2 * NE);
        const int p = rem / NE;
        const int e = rem - p * NE;
        const int b = b0 + bb;
        float acc = 0.0f;
        #pragma unroll
        for (int k = 0; k < KK; ++k) {
            const float d = src_pts[p * KK + k] + dest_offsets[b * 2 * KK + p * KK + k];
            acc = fmaf(d, L_inv[e * NE + 3 + k], acc);
        }
        s_coeff[bb][p][e] = acc;
    }
    __syncthreads();

    const int n = blockIdx.x * 256 + tid;

    // This pixel's right_mat column (each row-read coalesced across lanes).
    float rm[NE];
    #pragma unroll
    for (int e = 0; e < NE; ++e)
        rm[e] = right_mat[(size_t)e * NN + n];

    // Phase A: coords + issue all gathers (8 row loads in flight).
    float la[BPB][6], lb[BPB][6];
    float wa[BPB], wb[BPB], wc[BPB], wd[BPB];
    bool hi_a[BPB], hi_c[BPB];

    #pragma unroll
    for (int bb = 0; bb < BPB; ++bb) {
        float tx = 0.0f, ty = 0.0f;
        #pragma unroll
        for (int e = 0; e < NE; ++e) {
            tx = fmaf(s_coeff[bb][0][e], rm[e], tx);
            ty = fmaf(s_coeff[bb][1][e], rm[e], ty);
        }
        const float x = 0.5f * (tx + 1.0f) * (float)WW;
        const float y = 0.5f * (ty + 1.0f) * (float)HH;

        int x0 = (int)x;   // trunc toward zero, matches astype(int32)
        int x1 = x0 + 1;
        int y0 = (int)y;
        int y1 = y0 + 1;
        x0 = min(max(x0, 0), WW - 1);
        x1 = min(max(x1, 0), WW - 1);
        y0 = min(max(y0, 0), HH - 1);
        y1 = min(max(y1, 0), HH - 1);

        const float x0f = (float)x0, x1f = (float)x1;
        const float y0f = (float)y0, y1f = (float)y1;
        wa[bb] = (x1f - x) * (y1f - y);
        wb[bb] = (x1f - x) * (y - y0f);
        wc[bb] = (x - x0f) * (y1f - y);
        wd[bb] = (x - x0f) * (y - y0f);

        // Row-pair gather: 6 contiguous floats per row from xs = min(x0, W-2).
        const int xs = min(x0, WW - 2);
        hi_a[bb] = (x0 > xs);
        hi_c[bb] = (x1 > xs);

        const float* img = image + (size_t)(b0 + bb) * NN * CC;
        const float* rowA = img + ((size_t)y0 * WW + xs) * CC;
        const float* rowB = img + ((size_t)y1 * WW + xs) * CC;
        __builtin_memcpy(la[bb], rowA, 6 * sizeof(float));
        __builtin_memcpy(lb[bb], rowB, 6 * sizeof(float));
    }

    // Phase B: combine + store.
    float* __restrict__ o = out + (size_t)b0 * NN * CC + (size_t)n * CC;
    #pragma unroll
    for (int bb = 0; bb < BPB; ++bb) {
        float res[CC];
        #pragma unroll
        for (int c = 0; c < CC; ++c) {
            const float pa = hi_a[bb] ? la[bb][c + 3] : la[bb][c];
            const float pc = hi_c[bb] ? la[bb][c + 3] : la[bb][c];
            const float pb = hi_a[bb] ? lb[bb][c + 3] : lb[bb][c];
            const float pd = hi_c[bb] ? lb[bb][c + 3] : lb[bb][c];
            res[c] = wa[bb] * pa + wb[bb] * pb + wc[bb] * pc + wd[bb] * pd;
        }
        __builtin_memcpy(o + (size_t)bb * NN * CC, res, CC * sizeof(float));
    }
}

extern "C" void kernel_launch(void* const* d_in, const int* in_sizes, int n_in,
                              void* d_out, int out_size, void* d_ws, size_t ws_size,
                              hipStream_t stream) {
    const float* image        = (const float*)d_in[0];
    const float* dest_offsets = (const float*)d_in[1];
    const float* right_mat    = (const float*)d_in[2];
    const float* L_inv        = (const float*)d_in[3];
    const float* src_pts      = (const float*)d_in[4];
    float* out = (float*)d_out;

    dim3 grid(NN / 256, BB / BPB);
    dim3 block(256);
    hipLaunchKernelGGL(tps_kernel, grid, block, 0, stream,
                       image, dest_offsets, right_mat, L_inv, src_pts, out);
}

// Round 4
// 94.344 us; speedup vs baseline: 1.2761x; 1.0182x over previous
//
#include <hip/hip_runtime.h>

#define BB 32
#define HH 512
#define WW 512
#define CC 3
#define KK 16
#define NE 19        // K + 3
#define NN (HH * WW) // 262144
#define BPB 4        // batches per block
#define NCOEFF (BPB * 2 * NE) // 152

__global__ __launch_bounds__(256, 4) void tps_kernel(
    const float* __restrict__ image,        // (B,H,W,C)
    const float* __restrict__ dest_offsets, // (B, 2K)
    const float* __restrict__ right_mat,    // (NE, N)
    const float* __restrict__ L_inv,        // (NE, NE)
    const float* __restrict__ src_pts,      // (2, K)
    float* __restrict__ out)                // (B,H,W,C)
{
    __shared__ float s_coeff[BPB][2][NE];
    const int tid = threadIdx.x;
    const int b0 = blockIdx.y * BPB;

    // TPS coefficients for this block's batch group:
    // coeff[bb][p][e] = sum_k (src[p][k] + off[b][p*K+k]) * L_inv[e][3+k]
    if (tid < NCOEFF) {
        const int bb = tid / (2 * NE);
        const int rem = tid - bb * (2 * NE);
        const int p = rem / NE;
        const int e = rem - p * NE;
        const int b = b0 + bb;
        float acc = 0.0f;
        #pragma unroll
        for (int k = 0; k < KK; ++k) {
            const float d = src_pts[p * KK + k] + dest_offsets[b * 2 * KK + p * KK + k];
            acc = fmaf(d, L_inv[e * NE + 3 + k], acc);
        }
        s_coeff[bb][p][e] = acc;
    }
    __syncthreads();

    const int n = blockIdx.x * 256 + tid;

    // This pixel's right_mat column (each row-read coalesced across lanes).
    float rm[NE];
    #pragma unroll
    for (int e = 0; e < NE; ++e)
        rm[e] = right_mat[(size_t)e * NN + n];

    // Phase A1: coords, weights, gather addresses for ALL batches (VALU only).
    float wa[BPB], wb[BPB], wc[BPB], wd[BPB];
    bool hi_a[BPB], hi_c[BPB];
    const float* rowA[BPB];
    const float* rowB[BPB];

    #pragma unroll
    for (int bb = 0; bb < BPB; ++bb) {
        float tx = 0.0f, ty = 0.0f;
        #pragma unroll
        for (int e = 0; e < NE; ++e) {
            tx = fmaf(s_coeff[bb][0][e], rm[e], tx);
            ty = fmaf(s_coeff[bb][1][e], rm[e], ty);
        }
        const float x = 0.5f * (tx + 1.0f) * (float)WW;
        const float y = 0.5f * (ty + 1.0f) * (float)HH;

        int x0 = (int)x;   // trunc toward zero, matches astype(int32)
        int x1 = x0 + 1;
        int y0 = (int)y;
        int y1 = y0 + 1;
        x0 = min(max(x0, 0), WW - 1);
        x1 = min(max(x1, 0), WW - 1);
        y0 = min(max(y0, 0), HH - 1);
        y1 = min(max(y1, 0), HH - 1);

        const float x0f = (float)x0, x1f = (float)x1;
        const float y0f = (float)y0, y1f = (float)y1;
        wa[bb] = (x1f - x) * (y1f - y);
        wb[bb] = (x1f - x) * (y - y0f);
        wc[bb] = (x - x0f) * (y1f - y);
        wd[bb] = (x - x0f) * (y - y0f);

        const int xs = min(x0, WW - 2);
        hi_a[bb] = (x0 > xs);
        hi_c[bb] = (x1 > xs);

        const float* img = image + (size_t)(b0 + bb) * NN * CC;
        rowA[bb] = img + ((size_t)y0 * WW + xs) * CC;
        rowB[bb] = img + ((size_t)y1 * WW + xs) * CC;
    }

    // Phase A2: issue ALL 8 row loads back-to-back (stay in registers).
    float la[BPB][6], lb[BPB][6];
    #pragma unroll
    for (int bb = 0; bb < BPB; ++bb) {
        __builtin_memcpy(la[bb], rowA[bb], 6 * sizeof(float));
        __builtin_memcpy(lb[bb], rowB[bb], 6 * sizeof(float));
    }

    // Phase B: combine + store.
    float* __restrict__ o = out + (size_t)b0 * NN * CC + (size_t)n * CC;
    #pragma unroll
    for (int bb = 0; bb < BPB; ++bb) {
        float res[CC];
        #pragma unroll
        for (int c = 0; c < CC; ++c) {
            const float pa = hi_a[bb] ? la[bb][c + 3] : la[bb][c];
            const float pc = hi_c[bb] ? la[bb][c + 3] : la[bb][c];
            const float pb = hi_a[bb] ? lb[bb][c + 3] : lb[bb][c];
            const float pd = hi_c[bb] ? lb[bb][c + 3] : lb[bb][c];
            res[c] = wa[bb] * pa + wb[bb] * pb + wc[bb] * pc + wd[bb] * pd;
        }
        __builtin_memcpy(o + (size_t)bb * NN * CC, res, CC * sizeof(float));
    }
}

extern "C" void kernel_launch(void* const* d_in, const int* in_sizes, int n_in,
                              void* d_out, int out_size, void* d_ws, size_t ws_size,
                              hipStream_t stream) {
    const float* image        = (const float*)d_in[0];
    const float* dest_offsets = (const float*)d_in[1];
    const float* right_mat    = (const float*)d_in[2];
    const float* L_inv        = (const float*)d_in[3];
    const float* src_pts      = (const float*)d_in[4];
    float* out = (float*)d_out;

    dim3 grid(NN / 256, BB / BPB);
    dim3 block(256);
    hipLaunchKernelGGL(tps_kernel, grid, block, 0, stream,
                       image, dest_offsets, right_mat, L_inv, src_pts, out);
}